// Round 3
// baseline (580.050 us; speedup 1.0000x reference)
//
#include <hip/hip_runtime.h>
#include <hip/hip_bf16.h>
#include <math.h>

typedef __bf16 bf16x8 __attribute__((ext_vector_type(8)));
typedef float f32x4 __attribute__((ext_vector_type(4)));

#define DEVI __device__ __forceinline__

// async global->LDS, 16B per lane. LDS dest must be wave-uniform-base + lane*16
// (our tid*8-element layout satisfies this exactly).
DEVI void gload_lds16(const __bf16* g, __bf16* l) {
    __builtin_amdgcn_global_load_lds(
        (const __attribute__((address_space(1))) void*)g,
        (__attribute__((address_space(3))) void*)l, 16, 0, 0);
}

// ---------------------------------------------------------------------------
// dtype sniffer (tri-modal). flag[0]=1 -> inputs are fp32 storage.
__global__ void sniff_kernel(const unsigned short* __restrict__ x, int* flags) {
    const int tid = threadIdx.x;  // 256
    const unsigned short u = x[tid * 2];
    const int e = (u >> 7) & 0xFF;
    const int zero = (u == 0) ? 1 : 0;
    const int sane = ((e >= 0x71 && e <= 0x8E) || ((u & 0x7FFF) == 0)) ? 1 : 0;
    const unsigned long long mz = __ballot(zero != 0);
    const unsigned long long ms = __ballot(sane != 0);
    __shared__ int wz[4], wsn[4];
    if ((tid & 63) == 0) { wz[tid >> 6] = __popcll(mz); wsn[tid >> 6] = __popcll(ms); }
    __syncthreads();
    if (tid == 0) {
        const int nz = wz[0] + wz[1] + wz[2] + wz[3];
        const int ns = wsn[0] + wsn[1] + wsn[2] + wsn[3];
        flags[0] = (nz >= 192 || ns < 128) ? 1 : 0;
    }
}

// convert/copy one input array into canonical bf16 (n multiple of 8)
__global__ __launch_bounds__(256) void convert_kernel(const void* __restrict__ src,
                                                      __bf16* __restrict__ dst, int n,
                                                      const int* __restrict__ flags) {
    const int i = (blockIdx.x * 256 + threadIdx.x) * 8;
    if (i >= n) return;
    if (flags[0]) {
        const float* s = (const float*)src;
        bf16x8 o;
#pragma unroll
        for (int j = 0; j < 8; j++) o[j] = (__bf16)s[i + j];
        *(bf16x8*)(dst + i) = o;
    } else {
        *(uint4*)(dst + i) = *(const uint4*)((const __bf16*)src + i);
    }
}

// ---------------------------------------------------------------------------
// LayerNorm: one block per row of 1024, fp32 math, bf16 out
template <typename T>
__global__ __launch_bounds__(256) void ln_kernel(const T* __restrict__ x,
                                                 const __bf16* __restrict__ g,
                                                 const __bf16* __restrict__ b,
                                                 __bf16* __restrict__ out) {
    const size_t row = blockIdx.x;
    const T* xr = x + row * 1024;
    const int tid = threadIdx.x;
    float v[4];
#pragma unroll
    for (int i = 0; i < 4; i++) v[i] = (float)xr[tid * 4 + i];
    float s = v[0] + v[1] + v[2] + v[3];
    float s2 = v[0] * v[0] + v[1] * v[1] + v[2] * v[2] + v[3] * v[3];
#pragma unroll
    for (int m = 32; m >= 1; m >>= 1) {
        s += __shfl_xor(s, m, 64);
        s2 += __shfl_xor(s2, m, 64);
    }
    __shared__ float rs[4], rs2[4];
    const int wave = tid >> 6, lane = tid & 63;
    if (lane == 0) { rs[wave] = s; rs2[wave] = s2; }
    __syncthreads();
    s = rs[0] + rs[1] + rs[2] + rs[3];
    s2 = rs2[0] + rs2[1] + rs2[2] + rs2[3];
    const float mu = s * (1.0f / 1024.0f);
    const float var = s2 * (1.0f / 1024.0f) - mu * mu;
    const float inv = rsqrtf(var + 1e-5f);
#pragma unroll
    for (int i = 0; i < 4; i++) {
        const int c = tid * 4 + i;
        out[row * 1024 + c] = (__bf16)((v[i] - mu) * inv * (float)g[c] + (float)b[c]);
    }
}

// ---------------------------------------------------------------------------
// MFMA GEMM: C[M,N] = A[M,K] @ B[N,K]^T, bf16 in, fp32 acc, OutT out.
// 128x128 tile, BK=32, 256 threads (4 waves 2x2), 4x4 16x16x32 MFMA per wave.
// Round-3 structure:
//   - XCD-aware 8x8 super-tile block swizzle (round-2, kept: FETCH 147->58MB)
//   - 3-buffer LDS, depth-2 prefetch, COUNTED vmcnt(4) + raw s_barrier:
//     stage(t+1) stays in flight across the barrier; vmcnt never drains to 0
//     in the main loop (T4). Race-safe: stage(t+2) targets the buffer whose
//     reads completed before barrier t (ds_reads finish before each wave's
//     MFMAs, which precede its barrier arrival); the vmcnt wait is BEFORE the
//     barrier so stage(t) has landed wave-locally, and the barrier makes that
//     global. sched_barrier(0)+memory clobber stop ds_read hoisting (rule 18).
enum { EP_NONE = 0, EP_ELU1 = 1, EP_BIAS_GELU = 2, EP_BIAS_RES = 3 };

DEVI void fence_all() { __builtin_amdgcn_sched_barrier(0); asm volatile("" ::: "memory"); }

template <int EP, typename OutT>
__global__ __launch_bounds__(256, 2) void gemm_bt(
    const __bf16* __restrict__ A, const __bf16* __restrict__ B,
    const __bf16* __restrict__ bias, const float* __restrict__ resid,
    OutT* __restrict__ C, int M, int N, int K) {
    const int gx = gridDim.x, gy = gridDim.y;
    int bm = blockIdx.y, bn = blockIdx.x;
    {   // bijective XCD-chunked 8x8 super-tile remap (requires gx%8==0, nwg%64==0)
        const int nwg = gx * gy;
        if ((gx & 7) == 0 && (nwg & 63) == 0) {
            const int bid = bm * gx + bn;
            const int perx = nwg >> 3;                 // blocks per XCD
            const int gid = (bid & 7) * perx + (bid >> 3);
            const int stg = gid >> 6, pos = gid & 63;  // super-tile id / pos in 8x8
            const int stw = gx >> 3;                   // super-tiles per grid row
            bm = (stg / stw) * 8 + (pos >> 3);
            bn = (stg % stw) * 8 + (pos & 7);
        }
    }
    const int tid = threadIdx.x;
    const int wave = tid >> 6, lane = tid & 63;
    const int wm = wave & 1, wn = wave >> 1;
    const int lm = lane & 15, lq = lane >> 4;

    __shared__ __align__(16) __bf16 Asmem[3 * 128 * 32];
    __shared__ __align__(16) __bf16 Bsmem[3 * 128 * 32];

    f32x4 acc[4][4] = {};

    // staging: thread tid covers row sr=tid>>2, cols (tid&3)*8..+7 of the
    // [128][32] tile; LDS elem offset = tid*8 (linear in tid -> legal for
    // global_load_lds wave-uniform-base + lane*16B).
    const int sr = tid >> 2;
    const int sc = (tid & 3) << 3;

    const __bf16* pa0 = A + (size_t)(bm * 128 + sr) * K + sc;
    const __bf16* pa1 = pa0 + (size_t)64 * K;
    const __bf16* pb0 = B + (size_t)(bn * 128 + sr) * K + sc;
    const __bf16* pb1 = pb0 + (size_t)64 * K;

    const int nt = K >> 5;

#define STAGE(t, b)                                             \
    do {                                                        \
        const int k0_ = (t) << 5;                               \
        const int o_ = (b) * 4096;                              \
        gload_lds16(pa0 + k0_, &Asmem[o_ + tid * 8]);           \
        gload_lds16(pa1 + k0_, &Asmem[o_ + 2048 + tid * 8]);    \
        gload_lds16(pb0 + k0_, &Bsmem[o_ + tid * 8]);           \
        gload_lds16(pb1 + k0_, &Bsmem[o_ + 2048 + tid * 8]);    \
    } while (0)

    // prologue: 2 stages in flight (8 loads outstanding)
    STAGE(0, 0);
    if (nt > 1) STAGE(1, 1);

    int bc = 0;  // = t % 3
    for (int t = 0; t < nt; ++t) {
        // wait for stage(t) only: oldest 4 loads. Last iter: drain everything.
        if (t < nt - 1) asm volatile("s_waitcnt vmcnt(4)" ::: "memory");
        else            asm volatile("s_waitcnt vmcnt(0)" ::: "memory");
        __builtin_amdgcn_s_barrier();
        fence_all();
        if (t + 2 < nt) {
            int bp2 = bc + 2; if (bp2 >= 3) bp2 -= 3;
            STAGE(t + 2, bp2);
        }
        const int o = bc * 4096;
        bf16x8 af[4], bfv[4];
#pragma unroll
        for (int i = 0; i < 4; i++) {
            af[i]  = *(const bf16x8*)&Asmem[o + (wm * 64 + i * 16 + lm) * 32 + lq * 8];
            bfv[i] = *(const bf16x8*)&Bsmem[o + (wn * 64 + i * 16 + lm) * 32 + lq * 8];
        }
#pragma unroll
        for (int i = 0; i < 4; i++)
#pragma unroll
            for (int j = 0; j < 4; j++)
                acc[i][j] = __builtin_amdgcn_mfma_f32_16x16x32_bf16(af[i], bfv[j], acc[i][j], 0, 0, 0);
        if (++bc == 3) bc = 0;
    }
#undef STAGE

    const int row0 = bm * 128 + wm * 64;
    const int col0 = bn * 128 + wn * 64;
#pragma unroll
    for (int i = 0; i < 4; i++) {
#pragma unroll
        for (int j = 0; j < 4; j++) {
            const int col = col0 + j * 16 + lm;
#pragma unroll
            for (int r = 0; r < 4; r++) {
                const int row = row0 + i * 16 + lq * 4 + r;
                float v = acc[i][j][r];
                if (EP == EP_ELU1) {
                    v = (v > 0.0f) ? (v + 1.0f) : expf(v);  // elu(x)+1
                } else if (EP == EP_BIAS_GELU) {
                    v += (float)bias[col];
                    v = 0.5f * v * (1.0f + erff(v * 0.70710678118654752f));
                } else if (EP == EP_BIAS_RES) {
                    v += (float)bias[col];
                    v += resid[(size_t)row * N + col];
                }
                C[(size_t)row * N + col] = (OutT)v;
            }
        }
    }
}

// ---------------------------------------------------------------------------
// KV partials: block (nh, sc) computes KV[d,v] over 256 s-rows, plus Ksum
__global__ __launch_bounds__(256) void kv_kernel(const __bf16* __restrict__ Kf,
                                                 const __bf16* __restrict__ Vf,
                                                 float* __restrict__ pkv,
                                                 float* __restrict__ pks) {
    const int nh = blockIdx.x, sc = blockIdx.y;
    const int n = nh >> 3, h = nh & 7;
    const int tid = threadIdx.x;
    const int tv = tid & 15, td = tid >> 4;
    __shared__ __align__(16) __bf16 Kt[32 * 128];
    __shared__ __align__(16) __bf16 Vt[32 * 128];
    float acc[8][8] = {};
    float ks[8] = {};
    const size_t rowbase = (size_t)n * 4096 + (size_t)sc * 256;
    for (int s0 = 0; s0 < 256; s0 += 32) {
#pragma unroll
        for (int rep = 0; rep < 2; rep++) {
            const int s = tid + rep * 256;
            const int r = s >> 4, cs = (s & 15) * 8;
            const size_t gidx = (rowbase + s0 + r) * 1024 + h * 128 + cs;
            *(bf16x8*)&Kt[r * 128 + cs] = *(const bf16x8*)&Kf[gidx];
            *(bf16x8*)&Vt[r * 128 + cs] = *(const bf16x8*)&Vf[gidx];
        }
        __syncthreads();
#pragma unroll 4
        for (int s = 0; s < 32; s++) {
            const bf16x8 k8 = *(const bf16x8*)&Kt[s * 128 + td * 8];
            const bf16x8 v8 = *(const bf16x8*)&Vt[s * 128 + tv * 8];
            float kk[8], vv[8];
#pragma unroll
            for (int i = 0; i < 8; i++) { kk[i] = (float)k8[i]; vv[i] = (float)v8[i]; }
#pragma unroll
            for (int i = 0; i < 8; i++) {
                ks[i] += kk[i];
#pragma unroll
                for (int j = 0; j < 8; j++) acc[i][j] += kk[i] * vv[j];
            }
        }
        __syncthreads();
    }
    float* dst = pkv + ((size_t)sc * 16 + nh) * 16384;
#pragma unroll
    for (int i = 0; i < 8; i++)
#pragma unroll
        for (int j = 0; j < 8; j++)
            dst[(td * 8 + i) * 128 + tv * 8 + j] = acc[i][j];
    if (tv == 0) {
        float* ds2 = pks + ((size_t)sc * 16 + nh) * 128;
#pragma unroll
        for (int i = 0; i < 8; i++) ds2[td * 8 + i] = ks[i];
    }
}

__global__ __launch_bounds__(256) void kv_reduce(const float* __restrict__ pkv,
                                                 const float* __restrict__ pks,
                                                 __bf16* __restrict__ kvb,
                                                 float* __restrict__ ksf) {
    const int idx = blockIdx.x * 256 + threadIdx.x;
    float s = 0.0f;
#pragma unroll
    for (int c = 0; c < 16; c++) s += pkv[(size_t)c * 262144 + idx];
    kvb[idx] = (__bf16)s;
    if (idx < 2048) {
        float t = 0.0f;
#pragma unroll
        for (int c = 0; c < 16; c++) t += pks[c * 2048 + idx];
        ksf[idx] = t;
    }
}

__global__ __launch_bounds__(256) void z_kernel(const __bf16* __restrict__ Qf,
                                                const float* __restrict__ ksf,
                                                float* __restrict__ zbuf) {
    const int idx = blockIdx.x * 256 + threadIdx.x;
    const int h = idx & 7;
    const size_t row = (size_t)(idx >> 3);
    const __bf16* q = Qf + row * 1024 + h * 128;
    const float* ks = ksf + ((size_t)((row >> 12) * 8 + h)) * 128;
    float s = 0.0f;
    for (int d = 0; d < 128; d += 8) {
        const bf16x8 q8 = *(const bf16x8*)&q[d];
#pragma unroll
        for (int j = 0; j < 8; j++) s += (float)q8[j] * ks[d + j];
    }
    zbuf[idx] = 1.0f / (s + 1e-6f);
}

// attn out + residual: xmid = x + (Q @ KV) * z   (per head), fp32 out
__global__ __launch_bounds__(256, 2) void attn_out_kernel(
    const __bf16* __restrict__ x, const __bf16* __restrict__ Qf,
    const __bf16* __restrict__ kvb, const float* __restrict__ zbuf,
    float* __restrict__ xmid) {
    const int nh = blockIdx.x, lc = blockIdx.y;
    const int n = nh >> 3, h = nh & 7;
    const int tid = threadIdx.x;
    __shared__ __align__(16) __bf16 KVs[128 * 128];
    __shared__ __align__(16) __bf16 Qs[64 * 128];
    __shared__ float Zs[64];
    const __bf16* kv = kvb + (size_t)nh * 16384;
    for (int i = tid * 8; i < 16384; i += 2048)
        *(bf16x8*)&KVs[i] = *(const bf16x8*)&kv[i];
    const size_t gr0 = (size_t)n * 4096 + (size_t)lc * 64;
#pragma unroll
    for (int rep = 0; rep < 4; rep++) {
        const int s = tid + rep * 256;
        const int r = s >> 4, cs = (s & 15) * 8;
        *(bf16x8*)&Qs[r * 128 + cs] = *(const bf16x8*)&Qf[(gr0 + r) * 1024 + h * 128 + cs];
    }
    if (tid < 64) Zs[tid] = zbuf[(gr0 + tid) * 8 + h];
    __syncthreads();
    const int tv = (tid & 15) * 8;
    const int tr0 = (tid >> 4) * 4;
    float acc[4][8] = {};
    for (int d = 0; d < 128; d++) {
        const bf16x8 kv8 = *(const bf16x8*)&KVs[d * 128 + tv];
        float kf[8];
#pragma unroll
        for (int j = 0; j < 8; j++) kf[j] = (float)kv8[j];
#pragma unroll
        for (int rr = 0; rr < 4; rr++) {
            const float q = (float)Qs[(tr0 + rr) * 128 + d];
#pragma unroll
            for (int j = 0; j < 8; j++) acc[rr][j] += q * kf[j];
        }
    }
#pragma unroll
    for (int rr = 0; rr < 4; rr++) {
        const size_t gi = (gr0 + tr0 + rr) * 1024 + h * 128 + tv;
        const float z = Zs[tr0 + rr];
        const bf16x8 xr = *(const bf16x8*)&x[gi];
#pragma unroll
        for (int j = 0; j < 8; j++) xmid[gi + j] = (float)xr[j] + acc[rr][j] * z;
    }
}

// ---------------------------------------------------------------------------
extern "C" void kernel_launch(void* const* d_in, const int* in_sizes, int n_in,
                              void* d_out, int out_size, void* d_ws, size_t ws_size,
                              hipStream_t stream) {
    float* out = (float*)d_out;   // <-- output is FP32 (reference output dtype)
    char* ws = (char*)d_ws;

    const int nx = 8388608, nw = 1048576, nw1 = 4194304, nb1 = 4096, ng = 1024;
    size_t off = 0;
    __bf16* cx   = (__bf16*)(ws + off); off += (size_t)nx * 2;
    __bf16* cwq  = (__bf16*)(ws + off); off += (size_t)nw * 2;
    __bf16* cwk  = (__bf16*)(ws + off); off += (size_t)nw * 2;
    __bf16* cwv  = (__bf16*)(ws + off); off += (size_t)nw * 2;
    __bf16* cw1  = (__bf16*)(ws + off); off += (size_t)nw1 * 2;
    __bf16* cb1  = (__bf16*)(ws + off); off += (size_t)nb1 * 2;
    __bf16* cw2  = (__bf16*)(ws + off); off += (size_t)nw1 * 2;
    __bf16* cb2  = (__bf16*)(ws + off); off += (size_t)ng * 2;
    __bf16* cg1  = (__bf16*)(ws + off); off += (size_t)ng * 2;
    __bf16* cbe1 = (__bf16*)(ws + off); off += (size_t)ng * 2;
    __bf16* cg2  = (__bf16*)(ws + off); off += (size_t)ng * 2;
    __bf16* cbe2 = (__bf16*)(ws + off); off += (size_t)ng * 2;
    int* flags = (int*)(ws + off); off += 64;

    char* PB = ws + off;
    __bf16* x2   = (__bf16*)(PB);                 // LN1 out; later LN2 out
    __bf16* Qf   = (__bf16*)(PB + 16777216);
    float*  pkv  = (float*)(PB + 33554432);
    __bf16* hbuf = (__bf16*)(PB + 16777216);      // MLP h chunk (over Qf+pkv)
    __bf16* Kf   = (__bf16*)(PB + 50331648);
    __bf16* Vf   = (__bf16*)(PB + 67108864);
    float*  xmid = (float*)(PB + 50331648);       // fp32 (over Kf+Vf)
    float*  pks  = (float*)(PB + 83886080);
    float*  ksf  = (float*)(PB + 84017152);
    float*  zbuf = (float*)(PB + 84025344);
    __bf16* kvb  = (__bf16*)(PB + 84287488);      // ends PB+84,811,776

    // 0. sniff dtype + canonicalize inputs to bf16
    sniff_kernel<<<1, 256, 0, stream>>>((const unsigned short*)d_in[0], flags);
    convert_kernel<<<nx / 2048, 256, 0, stream>>>(d_in[0], cx, nx, flags);
    convert_kernel<<<nw / 2048, 256, 0, stream>>>(d_in[1], cwq, nw, flags);
    convert_kernel<<<nw / 2048, 256, 0, stream>>>(d_in[2], cwk, nw, flags);
    convert_kernel<<<nw / 2048, 256, 0, stream>>>(d_in[3], cwv, nw, flags);
    convert_kernel<<<nw1 / 2048, 256, 0, stream>>>(d_in[4], cw1, nw1, flags);
    convert_kernel<<<2, 256, 0, stream>>>(d_in[5], cb1, nb1, flags);
    convert_kernel<<<nw1 / 2048, 256, 0, stream>>>(d_in[6], cw2, nw1, flags);
    convert_kernel<<<1, 256, 0, stream>>>(d_in[7], cb2, ng, flags);
    convert_kernel<<<1, 256, 0, stream>>>(d_in[8], cg1, ng, flags);
    convert_kernel<<<1, 256, 0, stream>>>(d_in[9], cbe1, ng, flags);
    convert_kernel<<<1, 256, 0, stream>>>(d_in[10], cg2, ng, flags);
    convert_kernel<<<1, 256, 0, stream>>>(d_in[11], cbe2, ng, flags);

    // 1. LN1
    ln_kernel<__bf16><<<8192, 256, 0, stream>>>(cx, cg1, cbe1, x2);
    // 2. QKV projections (elu+1 fused for Q,K; v/L * L cancels so V is raw)
    dim3 gqkv(1024 / 128, 8192 / 128);
    gemm_bt<EP_ELU1, __bf16><<<gqkv, 256, 0, stream>>>(x2, cwq, nullptr, nullptr, Qf, 8192, 1024, 1024);
    gemm_bt<EP_ELU1, __bf16><<<gqkv, 256, 0, stream>>>(x2, cwk, nullptr, nullptr, Kf, 8192, 1024, 1024);
    gemm_bt<EP_NONE, __bf16><<<gqkv, 256, 0, stream>>>(x2, cwv, nullptr, nullptr, Vf, 8192, 1024, 1024);
    // 3. KV + Ksum
    kv_kernel<<<dim3(16, 16), 256, 0, stream>>>(Kf, Vf, pkv, pks);
    kv_reduce<<<1024, 256, 0, stream>>>(pkv, pks, kvb, ksf);
    // 4. Z, attention out + residual -> xmid fp32 (over dead Kf/Vf)
    z_kernel<<<256, 256, 0, stream>>>(Qf, ksf, zbuf);
    attn_out_kernel<<<dim3(16, 64), 256, 0, stream>>>(cx, Qf, kvb, zbuf, xmid);
    // 5. LN2 + chunked MLP; final epilogue writes FP32 out
    ln_kernel<float><<<8192, 256, 0, stream>>>(xmid, cg2, cbe2, x2);
    for (int c = 0; c < 2; c++) {
        const size_t ro = (size_t)c * 4096;
        gemm_bt<EP_BIAS_GELU, __bf16><<<dim3(4096 / 128, 4096 / 128), 256, 0, stream>>>(
            x2 + ro * 1024, cw1, cb1, nullptr, hbuf, 4096, 4096, 1024);
        gemm_bt<EP_BIAS_RES, float><<<dim3(1024 / 128, 4096 / 128), 256, 0, stream>>>(
            hbuf, cw2, cb2, xmid + ro * 1024, out + ro * 1024, 4096, 1024, 4096);
    }
}

// Round 4
// 468.878 us; speedup vs baseline: 1.2371x; 1.2371x over previous
//
#include <hip/hip_runtime.h>
#include <hip/hip_bf16.h>
#include <math.h>

typedef __bf16 bf16x8 __attribute__((ext_vector_type(8)));
typedef float f32x4 __attribute__((ext_vector_type(4)));

#define DEVI __device__ __forceinline__

// async global->LDS, 16B per lane. LDS dest must be wave-uniform-base + lane*16
// (our tid*8-element layout satisfies this exactly).
DEVI void gload_lds16(const __bf16* g, __bf16* l) {
    __builtin_amdgcn_global_load_lds(
        (const __attribute__((address_space(1))) void*)g,
        (__attribute__((address_space(3))) void*)l, 16, 0, 0);
}

// ---------------------------------------------------------------------------
// dtype sniffer (tri-modal). flag[0]=1 -> inputs are fp32 storage.
__global__ void sniff_kernel(const unsigned short* __restrict__ x, int* flags) {
    const int tid = threadIdx.x;  // 256
    const unsigned short u = x[tid * 2];
    const int e = (u >> 7) & 0xFF;
    const int zero = (u == 0) ? 1 : 0;
    const int sane = ((e >= 0x71 && e <= 0x8E) || ((u & 0x7FFF) == 0)) ? 1 : 0;
    const unsigned long long mz = __ballot(zero != 0);
    const unsigned long long ms = __ballot(sane != 0);
    __shared__ int wz[4], wsn[4];
    if ((tid & 63) == 0) { wz[tid >> 6] = __popcll(mz); wsn[tid >> 6] = __popcll(ms); }
    __syncthreads();
    if (tid == 0) {
        const int nz = wz[0] + wz[1] + wz[2] + wz[3];
        const int ns = wsn[0] + wsn[1] + wsn[2] + wsn[3];
        flags[0] = (nz >= 192 || ns < 128) ? 1 : 0;
    }
}

// convert/copy one input array into canonical bf16 (n multiple of 8)
__global__ __launch_bounds__(256) void convert_kernel(const void* __restrict__ src,
                                                      __bf16* __restrict__ dst, int n,
                                                      const int* __restrict__ flags) {
    const int i = (blockIdx.x * 256 + threadIdx.x) * 8;
    if (i >= n) return;
    if (flags[0]) {
        const float* s = (const float*)src;
        bf16x8 o;
#pragma unroll
        for (int j = 0; j < 8; j++) o[j] = (__bf16)s[i + j];
        *(bf16x8*)(dst + i) = o;
    } else {
        *(uint4*)(dst + i) = *(const uint4*)((const __bf16*)src + i);
    }
}

// ---------------------------------------------------------------------------
// LayerNorm: one block per row of 1024, fp32 math, bf16 out
template <typename T>
__global__ __launch_bounds__(256) void ln_kernel(const T* __restrict__ x,
                                                 const __bf16* __restrict__ g,
                                                 const __bf16* __restrict__ b,
                                                 __bf16* __restrict__ out) {
    const size_t row = blockIdx.x;
    const T* xr = x + row * 1024;
    const int tid = threadIdx.x;
    float v[4];
#pragma unroll
    for (int i = 0; i < 4; i++) v[i] = (float)xr[tid * 4 + i];
    float s = v[0] + v[1] + v[2] + v[3];
    float s2 = v[0] * v[0] + v[1] * v[1] + v[2] * v[2] + v[3] * v[3];
#pragma unroll
    for (int m = 32; m >= 1; m >>= 1) {
        s += __shfl_xor(s, m, 64);
        s2 += __shfl_xor(s2, m, 64);
    }
    __shared__ float rs[4], rs2[4];
    const int wave = tid >> 6, lane = tid & 63;
    if (lane == 0) { rs[wave] = s; rs2[wave] = s2; }
    __syncthreads();
    s = rs[0] + rs[1] + rs[2] + rs[3];
    s2 = rs2[0] + rs2[1] + rs2[2] + rs2[3];
    const float mu = s * (1.0f / 1024.0f);
    const float var = s2 * (1.0f / 1024.0f) - mu * mu;
    const float inv = rsqrtf(var + 1e-5f);
#pragma unroll
    for (int i = 0; i < 4; i++) {
        const int c = tid * 4 + i;
        out[row * 1024 + c] = (__bf16)((v[i] - mu) * inv * (float)g[c] + (float)b[c]);
    }
}

// ---------------------------------------------------------------------------
// MFMA GEMM: C[M,N] = A[M,K] @ B[N,K]^T, bf16 in, fp32 acc, OutT out.
// 128x128 tile, BK=32, 256 threads (4 waves 2x2), 4x4 16x16x32 MFMA per wave.
// Round-4 structure:
//   - SIX DISTINCT __shared__ arrays (3 K-tile buffers x A,B), K-loop unrolled
//     by 3 so every LDS base is a compile-time object. Hypothesis: the waitcnt
//     pass can then prove pending LDS-DMA (stage t+1/t+2) doesn't alias the
//     ds_read source buffer, so the counted vmcnt(4) survives and prefetch
//     stays in flight across the barrier (rounds 1-3 all serialized on an
//     inserted vmcnt(0) due to runtime-offset single-array aliasing).
//   - XCD-aware 8x8 super-tile block swizzle (kept: FETCH 147->58MB).
//   NOTE: K-tail logic assumes nt % 3 == 2 (true for K=1024/4096 -> nt=32/128)
//   or falls back to safe vmcnt(0) drains in the tail.
enum { EP_NONE = 0, EP_ELU1 = 1, EP_BIAS_GELU = 2, EP_BIAS_RES = 3, EP_QKV = 4 };

#define READMM(RA, RB)                                                        \
    do {                                                                      \
        bf16x8 af_[4], bfv_[4];                                               \
        _Pragma("unroll") for (int i_ = 0; i_ < 4; i_++) {                    \
            af_[i_]  = *(const bf16x8*)&RA[(wm * 64 + i_ * 16 + lm) * 32 + lq * 8]; \
            bfv_[i_] = *(const bf16x8*)&RB[(wn * 64 + i_ * 16 + lm) * 32 + lq * 8]; \
        }                                                                     \
        _Pragma("unroll") for (int i_ = 0; i_ < 4; i_++)                      \
            _Pragma("unroll") for (int j_ = 0; j_ < 4; j_++)                  \
                acc[i_][j_] = __builtin_amdgcn_mfma_f32_16x16x32_bf16(        \
                    af_[i_], bfv_[j_], acc[i_][j_], 0, 0, 0);                 \
    } while (0)

#define KBODY(RA, RB, SA, SB, TS, WAITN)                                      \
    do {                                                                      \
        asm volatile("s_waitcnt vmcnt(" #WAITN ")" ::: "memory");             \
        __builtin_amdgcn_s_barrier();                                         \
        __builtin_amdgcn_sched_barrier(0);                                    \
        if ((TS) < nt) {                                                      \
            const int k0_ = (TS) << 5;                                        \
            gload_lds16(pa0 + k0_, &SA[tid * 8]);                             \
            gload_lds16(pa1 + k0_, &SA[2048 + tid * 8]);                      \
            gload_lds16(pb0 + k0_, &SB[tid * 8]);                             \
            gload_lds16(pb1 + k0_, &SB[2048 + tid * 8]);                      \
        }                                                                     \
        READMM(RA, RB);                                                       \
    } while (0)

template <int EP, typename OutT>
__global__ __launch_bounds__(256, 3) void gemm_bt(
    const __bf16* __restrict__ A, const __bf16* __restrict__ B,
    const __bf16* __restrict__ bias, const float* __restrict__ resid,
    OutT* __restrict__ C, int M, int N, int K) {
    const int gx = gridDim.x, gy = gridDim.y;
    int bm = blockIdx.y, bn = blockIdx.x;
    {   // bijective XCD-chunked 8x8 super-tile remap (requires gx%8==0, nwg%64==0)
        const int nwg = gx * gy;
        if ((gx & 7) == 0 && (nwg & 63) == 0) {
            const int bid = bm * gx + bn;
            const int perx = nwg >> 3;                 // blocks per XCD
            const int gid = (bid & 7) * perx + (bid >> 3);
            const int stg = gid >> 6, pos = gid & 63;  // super-tile id / pos in 8x8
            const int stw = gx >> 3;                   // super-tiles per grid row
            bm = (stg / stw) * 8 + (pos >> 3);
            bn = (stg % stw) * 8 + (pos & 7);
        }
    }
    const int tid = threadIdx.x;
    const int wave = tid >> 6, lane = tid & 63;
    const int wm = wave & 1, wn = wave >> 1;
    const int lm = lane & 15, lq = lane >> 4;

    // three distinct K-tile buffers per operand: compile-time disjoint objects
    __shared__ __align__(16) __bf16 As0[128 * 32];
    __shared__ __align__(16) __bf16 As1[128 * 32];
    __shared__ __align__(16) __bf16 As2[128 * 32];
    __shared__ __align__(16) __bf16 Bs0[128 * 32];
    __shared__ __align__(16) __bf16 Bs1[128 * 32];
    __shared__ __align__(16) __bf16 Bs2[128 * 32];

    f32x4 acc[4][4] = {};

    // staging: thread tid covers row sr=tid>>2, cols (tid&3)*8..+7 of the
    // [128][32] tile; LDS elem offset = tid*8 (linear in tid -> legal for
    // global_load_lds wave-uniform-base + lane*16B).
    const int sr = tid >> 2;
    const int sc = (tid & 3) << 3;

    const __bf16* pa0 = A + (size_t)(bm * 128 + sr) * K + sc;
    const __bf16* pa1 = pa0 + (size_t)64 * K;
    const __bf16* pb0 = B + (size_t)(bn * 128 + sr) * K + sc;
    const __bf16* pb1 = pb0 + (size_t)64 * K;

    const int nt = K >> 5;

    // prologue: stage tiles 0,1 (8 loads in flight)
    gload_lds16(pa0, &As0[tid * 8]);
    gload_lds16(pa1, &As0[2048 + tid * 8]);
    gload_lds16(pb0, &Bs0[tid * 8]);
    gload_lds16(pb1, &Bs0[2048 + tid * 8]);
    if (nt > 1) {
        gload_lds16(pa0 + 32, &As1[tid * 8]);
        gload_lds16(pa1 + 32, &As1[2048 + tid * 8]);
        gload_lds16(pb0 + 32, &Bs1[tid * 8]);
        gload_lds16(pb1 + 32, &Bs1[2048 + tid * 8]);
    }

    int t = 0;
    for (; t + 2 < nt; t += 3) {
        KBODY(As0, Bs0, As2, Bs2, t + 2, 4);
        KBODY(As1, Bs1, As0, Bs0, t + 3, 4);
        KBODY(As2, Bs2, As1, Bs1, t + 4, 4);
    }
    // tail (t is a multiple of 3 -> current buffer is #0); safe full drains
    if (t < nt) {
        asm volatile("s_waitcnt vmcnt(0)" ::: "memory");
        __builtin_amdgcn_s_barrier();
        __builtin_amdgcn_sched_barrier(0);
        READMM(As0, Bs0);
        t++;
        if (t < nt) { READMM(As1, Bs1); }
    }

    const int row0 = bm * 128 + wm * 64;
    const int col0 = bn * 128 + wn * 64;
#pragma unroll
    for (int i = 0; i < 4; i++) {
#pragma unroll
        for (int j = 0; j < 4; j++) {
            const int col = col0 + j * 16 + lm;
#pragma unroll
            for (int r = 0; r < 4; r++) {
                const int row = row0 + i * 16 + lq * 4 + r;
                float v = acc[i][j][r];
                if (EP == EP_QKV) {
                    // fused QKV: col region 0/1/2 -> Q/K/V outputs [8192,1024];
                    // elu+1 on Q,K only. Region is block-uniform (col0 step 64).
                    float vv = (col < 2048) ? ((v > 0.0f) ? (v + 1.0f) : expf(v)) : v;
                    __bf16* dst = (col < 1024) ? (__bf16*)C
                                : (col < 2048) ? (__bf16*)const_cast<__bf16*>(bias)
                                               : (__bf16*)const_cast<float*>(resid);
                    dst[(size_t)row * 1024 + (col & 1023)] = (__bf16)vv;
                } else {
                    if (EP == EP_ELU1) {
                        v = (v > 0.0f) ? (v + 1.0f) : expf(v);  // elu(x)+1
                    } else if (EP == EP_BIAS_GELU) {
                        v += (float)bias[col];
                        v = 0.5f * v * (1.0f + erff(v * 0.70710678118654752f));
                    } else if (EP == EP_BIAS_RES) {
                        v += (float)bias[col];
                        v += resid[(size_t)row * N + col];
                    }
                    C[(size_t)row * N + col] = (OutT)v;
                }
            }
        }
    }
}

// ---------------------------------------------------------------------------
// KV partials: block (nh, sc) computes KV[d,v] over 256 s-rows, plus Ksum
__global__ __launch_bounds__(256) void kv_kernel(const __bf16* __restrict__ Kf,
                                                 const __bf16* __restrict__ Vf,
                                                 float* __restrict__ pkv,
                                                 float* __restrict__ pks) {
    const int nh = blockIdx.x, sc = blockIdx.y;
    const int n = nh >> 3, h = nh & 7;
    const int tid = threadIdx.x;
    const int tv = tid & 15, td = tid >> 4;
    __shared__ __align__(16) __bf16 Kt[32 * 128];
    __shared__ __align__(16) __bf16 Vt[32 * 128];
    float acc[8][8] = {};
    float ks[8] = {};
    const size_t rowbase = (size_t)n * 4096 + (size_t)sc * 256;
    for (int s0 = 0; s0 < 256; s0 += 32) {
#pragma unroll
        for (int rep = 0; rep < 2; rep++) {
            const int s = tid + rep * 256;
            const int r = s >> 4, cs = (s & 15) * 8;
            const size_t gidx = (rowbase + s0 + r) * 1024 + h * 128 + cs;
            *(bf16x8*)&Kt[r * 128 + cs] = *(const bf16x8*)&Kf[gidx];
            *(bf16x8*)&Vt[r * 128 + cs] = *(const bf16x8*)&Vf[gidx];
        }
        __syncthreads();
#pragma unroll 4
        for (int s = 0; s < 32; s++) {
            const bf16x8 k8 = *(const bf16x8*)&Kt[s * 128 + td * 8];
            const bf16x8 v8 = *(const bf16x8*)&Vt[s * 128 + tv * 8];
            float kk[8], vv[8];
#pragma unroll
            for (int i = 0; i < 8; i++) { kk[i] = (float)k8[i]; vv[i] = (float)v8[i]; }
#pragma unroll
            for (int i = 0; i < 8; i++) {
                ks[i] += kk[i];
#pragma unroll
                for (int j = 0; j < 8; j++) acc[i][j] += kk[i] * vv[j];
            }
        }
        __syncthreads();
    }
    float* dst = pkv + ((size_t)sc * 16 + nh) * 16384;
#pragma unroll
    for (int i = 0; i < 8; i++)
#pragma unroll
        for (int j = 0; j < 8; j++)
            dst[(td * 8 + i) * 128 + tv * 8 + j] = acc[i][j];
    if (tv == 0) {
        float* ds2 = pks + ((size_t)sc * 16 + nh) * 128;
#pragma unroll
        for (int i = 0; i < 8; i++) ds2[td * 8 + i] = ks[i];
    }
}

__global__ __launch_bounds__(256) void kv_reduce(const float* __restrict__ pkv,
                                                 const float* __restrict__ pks,
                                                 __bf16* __restrict__ kvb,
                                                 float* __restrict__ ksf) {
    const int idx = blockIdx.x * 256 + threadIdx.x;
    float s = 0.0f;
#pragma unroll
    for (int c = 0; c < 16; c++) s += pkv[(size_t)c * 262144 + idx];
    kvb[idx] = (__bf16)s;
    if (idx < 2048) {
        float t = 0.0f;
#pragma unroll
        for (int c = 0; c < 16; c++) t += pks[c * 2048 + idx];
        ksf[idx] = t;
    }
}

__global__ __launch_bounds__(256) void z_kernel(const __bf16* __restrict__ Qf,
                                                const float* __restrict__ ksf,
                                                float* __restrict__ zbuf) {
    const int idx = blockIdx.x * 256 + threadIdx.x;
    const int h = idx & 7;
    const size_t row = (size_t)(idx >> 3);
    const __bf16* q = Qf + row * 1024 + h * 128;
    const float* ks = ksf + ((size_t)((row >> 12) * 8 + h)) * 128;
    float s = 0.0f;
    for (int d = 0; d < 128; d += 8) {
        const bf16x8 q8 = *(const bf16x8*)&q[d];
#pragma unroll
        for (int j = 0; j < 8; j++) s += (float)q8[j] * ks[d + j];
    }
    zbuf[idx] = 1.0f / (s + 1e-6f);
}

// attn out + residual: xmid = x + (Q @ KV) * z   (per head), fp32 out
__global__ __launch_bounds__(256, 2) void attn_out_kernel(
    const __bf16* __restrict__ x, const __bf16* __restrict__ Qf,
    const __bf16* __restrict__ kvb, const float* __restrict__ zbuf,
    float* __restrict__ xmid) {
    const int nh = blockIdx.x, lc = blockIdx.y;
    const int n = nh >> 3, h = nh & 7;
    const int tid = threadIdx.x;
    __shared__ __align__(16) __bf16 KVs[128 * 128];
    __shared__ __align__(16) __bf16 Qs[64 * 128];
    __shared__ float Zs[64];
    const __bf16* kv = kvb + (size_t)nh * 16384;
    for (int i = tid * 8; i < 16384; i += 2048)
        *(bf16x8*)&KVs[i] = *(const bf16x8*)&kv[i];
    const size_t gr0 = (size_t)n * 4096 + (size_t)lc * 64;
#pragma unroll
    for (int rep = 0; rep < 4; rep++) {
        const int s = tid + rep * 256;
        const int r = s >> 4, cs = (s & 15) * 8;
        *(bf16x8*)&Qs[r * 128 + cs] = *(const bf16x8*)&Qf[(gr0 + r) * 1024 + h * 128 + cs];
    }
    if (tid < 64) Zs[tid] = zbuf[(gr0 + tid) * 8 + h];
    __syncthreads();
    const int tv = (tid & 15) * 8;
    const int tr0 = (tid >> 4) * 4;
    float acc[4][8] = {};
    for (int d = 0; d < 128; d++) {
        const bf16x8 kv8 = *(const bf16x8*)&KVs[d * 128 + tv];
        float kf[8];
#pragma unroll
        for (int j = 0; j < 8; j++) kf[j] = (float)kv8[j];
#pragma unroll
        for (int rr = 0; rr < 4; rr++) {
            const float q = (float)Qs[(tr0 + rr) * 128 + d];
#pragma unroll
            for (int j = 0; j < 8; j++) acc[rr][j] += q * kf[j];
        }
    }
#pragma unroll
    for (int rr = 0; rr < 4; rr++) {
        const size_t gi = (gr0 + tr0 + rr) * 1024 + h * 128 + tv;
        const float z = Zs[tr0 + rr];
        const bf16x8 xr = *(const bf16x8*)&x[gi];
#pragma unroll
        for (int j = 0; j < 8; j++) xmid[gi + j] = (float)xr[j] + acc[rr][j] * z;
    }
}

// ---------------------------------------------------------------------------
extern "C" void kernel_launch(void* const* d_in, const int* in_sizes, int n_in,
                              void* d_out, int out_size, void* d_ws, size_t ws_size,
                              hipStream_t stream) {
    float* out = (float*)d_out;   // <-- output is FP32 (reference output dtype)
    char* ws = (char*)d_ws;

    const int nx = 8388608, nw = 1048576, nw1 = 4194304, nb1 = 4096, ng = 1024;
    size_t off = 0;
    __bf16* cx   = (__bf16*)(ws + off); off += (size_t)nx * 2;
    __bf16* cwq  = (__bf16*)(ws + off); off += (size_t)nw * 2;   // cwq/cwk/cwv
    __bf16* cwk  = (__bf16*)(ws + off); off += (size_t)nw * 2;   // contiguous =
    __bf16* cwv  = (__bf16*)(ws + off); off += (size_t)nw * 2;   // B[3072,1024]
    __bf16* cw1  = (__bf16*)(ws + off); off += (size_t)nw1 * 2;
    __bf16* cb1  = (__bf16*)(ws + off); off += (size_t)nb1 * 2;
    __bf16* cw2  = (__bf16*)(ws + off); off += (size_t)nw1 * 2;
    __bf16* cb2  = (__bf16*)(ws + off); off += (size_t)ng * 2;
    __bf16* cg1  = (__bf16*)(ws + off); off += (size_t)ng * 2;
    __bf16* cbe1 = (__bf16*)(ws + off); off += (size_t)ng * 2;
    __bf16* cg2  = (__bf16*)(ws + off); off += (size_t)ng * 2;
    __bf16* cbe2 = (__bf16*)(ws + off); off += (size_t)ng * 2;
    int* flags = (int*)(ws + off); off += 64;

    char* PB = ws + off;
    __bf16* x2   = (__bf16*)(PB);                 // LN1 out; later LN2 out
    __bf16* Qf   = (__bf16*)(PB + 16777216);
    float*  pkv  = (float*)(PB + 33554432);
    __bf16* hbuf = (__bf16*)(PB + 16777216);      // MLP h chunk (over Qf+pkv)
    __bf16* Kf   = (__bf16*)(PB + 50331648);
    __bf16* Vf   = (__bf16*)(PB + 67108864);
    float*  xmid = (float*)(PB + 50331648);       // fp32 (over Kf+Vf)
    float*  pks  = (float*)(PB + 83886080);
    float*  ksf  = (float*)(PB + 84017152);
    float*  zbuf = (float*)(PB + 84025344);
    __bf16* kvb  = (__bf16*)(PB + 84287488);      // ends PB+84,811,776

    // 0. sniff dtype + canonicalize inputs to bf16
    sniff_kernel<<<1, 256, 0, stream>>>((const unsigned short*)d_in[0], flags);
    convert_kernel<<<nx / 2048, 256, 0, stream>>>(d_in[0], cx, nx, flags);
    convert_kernel<<<nw / 2048, 256, 0, stream>>>(d_in[1], cwq, nw, flags);
    convert_kernel<<<nw / 2048, 256, 0, stream>>>(d_in[2], cwk, nw, flags);
    convert_kernel<<<nw / 2048, 256, 0, stream>>>(d_in[3], cwv, nw, flags);
    convert_kernel<<<nw1 / 2048, 256, 0, stream>>>(d_in[4], cw1, nw1, flags);
    convert_kernel<<<2, 256, 0, stream>>>(d_in[5], cb1, nb1, flags);
    convert_kernel<<<nw1 / 2048, 256, 0, stream>>>(d_in[6], cw2, nw1, flags);
    convert_kernel<<<1, 256, 0, stream>>>(d_in[7], cb2, ng, flags);
    convert_kernel<<<1, 256, 0, stream>>>(d_in[8], cg1, ng, flags);
    convert_kernel<<<1, 256, 0, stream>>>(d_in[9], cbe1, ng, flags);
    convert_kernel<<<1, 256, 0, stream>>>(d_in[10], cg2, ng, flags);
    convert_kernel<<<1, 256, 0, stream>>>(d_in[11], cbe2, ng, flags);

    // 1. LN1
    ln_kernel<__bf16><<<8192, 256, 0, stream>>>(cx, cg1, cbe1, x2);
    // 2. fused QKV projection: B = [wq;wk;wv] (contiguous), N=3072.
    //    Epilogue routes col regions to Qf/Kf/Vf; elu+1 on Q,K (v/L*L cancels).
    gemm_bt<EP_QKV, __bf16><<<dim3(3072 / 128, 8192 / 128), 256, 0, stream>>>(
        x2, cwq, (const __bf16*)Kf, (const float*)Vf, Qf, 8192, 3072, 1024);
    // 3. KV + Ksum
    kv_kernel<<<dim3(16, 16), 256, 0, stream>>>(Kf, Vf, pkv, pks);
    kv_reduce<<<1024, 256, 0, stream>>>(pkv, pks, kvb, ksf);
    // 4. Z, attention out + residual -> xmid fp32 (over dead Kf/Vf)
    z_kernel<<<256, 256, 0, stream>>>(Qf, ksf, zbuf);
    attn_out_kernel<<<dim3(16, 64), 256, 0, stream>>>(cx, Qf, kvb, zbuf, xmid);
    // 5. LN2 + chunked MLP; final epilogue writes FP32 out
    ln_kernel<float><<<8192, 256, 0, stream>>>(xmid, cg2, cbe2, x2);
    for (int c = 0; c < 2; c++) {
        const size_t ro = (size_t)c * 4096;
        gemm_bt<EP_BIAS_GELU, __bf16><<<dim3(4096 / 128, 4096 / 128), 256, 0, stream>>>(
            x2 + ro * 1024, cw1, cb1, nullptr, hbuf, 4096, 4096, 1024);
        gemm_bt<EP_BIAS_RES, float><<<dim3(1024 / 128, 4096 / 128), 256, 0, stream>>>(
            hbuf, cw2, cb2, xmid + ro * 1024, out + ro * 1024, 4096, 1024, 4096);
    }
}

// Round 5
// 455.035 us; speedup vs baseline: 1.2747x; 1.0304x over previous
//
#include <hip/hip_runtime.h>
#include <hip/hip_bf16.h>
#include <math.h>

typedef __bf16 bf16x8 __attribute__((ext_vector_type(8)));
typedef float f32x4 __attribute__((ext_vector_type(4)));

#define DEVI __device__ __forceinline__

// async global->LDS, 16B per lane. LDS dest must be wave-uniform-base + lane*16
// (our tid*8-element layout satisfies this exactly).
DEVI void gload_lds16(const __bf16* g, __bf16* l) {
    __builtin_amdgcn_global_load_lds(
        (const __attribute__((address_space(1))) void*)g,
        (__attribute__((address_space(3))) void*)l, 16, 0, 0);
}

// ---------------------------------------------------------------------------
// dtype sniffer (tri-modal). flag[0]=1 -> inputs are fp32 storage.
__global__ void sniff_kernel(const unsigned short* __restrict__ x, int* flags) {
    const int tid = threadIdx.x;  // 256
    const unsigned short u = x[tid * 2];
    const int e = (u >> 7) & 0xFF;
    const int zero = (u == 0) ? 1 : 0;
    const int sane = ((e >= 0x71 && e <= 0x8E) || ((u & 0x7FFF) == 0)) ? 1 : 0;
    const unsigned long long mz = __ballot(zero != 0);
    const unsigned long long ms = __ballot(sane != 0);
    __shared__ int wz[4], wsn[4];
    if ((tid & 63) == 0) { wz[tid >> 6] = __popcll(mz); wsn[tid >> 6] = __popcll(ms); }
    __syncthreads();
    if (tid == 0) {
        const int nz = wz[0] + wz[1] + wz[2] + wz[3];
        const int ns = wsn[0] + wsn[1] + wsn[2] + wsn[3];
        flags[0] = (nz >= 192 || ns < 128) ? 1 : 0;
    }
}

// convert/copy one input array into canonical bf16 (n multiple of 8)
__global__ __launch_bounds__(256) void convert_kernel(const void* __restrict__ src,
                                                      __bf16* __restrict__ dst, int n,
                                                      const int* __restrict__ flags) {
    const int i = (blockIdx.x * 256 + threadIdx.x) * 8;
    if (i >= n) return;
    if (flags[0]) {
        const float* s = (const float*)src;
        bf16x8 o;
#pragma unroll
        for (int j = 0; j < 8; j++) o[j] = (__bf16)s[i + j];
        *(bf16x8*)(dst + i) = o;
    } else {
        *(uint4*)(dst + i) = *(const uint4*)((const __bf16*)src + i);
    }
}

// ---------------------------------------------------------------------------
// LayerNorm: one block per row of 1024, fp32 math, bf16 out
template <typename T>
__global__ __launch_bounds__(256) void ln_kernel(const T* __restrict__ x,
                                                 const __bf16* __restrict__ g,
                                                 const __bf16* __restrict__ b,
                                                 __bf16* __restrict__ out) {
    const size_t row = blockIdx.x;
    const T* xr = x + row * 1024;
    const int tid = threadIdx.x;
    float v[4];
#pragma unroll
    for (int i = 0; i < 4; i++) v[i] = (float)xr[tid * 4 + i];
    float s = v[0] + v[1] + v[2] + v[3];
    float s2 = v[0] * v[0] + v[1] * v[1] + v[2] * v[2] + v[3] * v[3];
#pragma unroll
    for (int m = 32; m >= 1; m >>= 1) {
        s += __shfl_xor(s, m, 64);
        s2 += __shfl_xor(s2, m, 64);
    }
    __shared__ float rs[4], rs2[4];
    const int wave = tid >> 6, lane = tid & 63;
    if (lane == 0) { rs[wave] = s; rs2[wave] = s2; }
    __syncthreads();
    s = rs[0] + rs[1] + rs[2] + rs[3];
    s2 = rs2[0] + rs2[1] + rs2[2] + rs2[3];
    const float mu = s * (1.0f / 1024.0f);
    const float var = s2 * (1.0f / 1024.0f) - mu * mu;
    const float inv = rsqrtf(var + 1e-5f);
#pragma unroll
    for (int i = 0; i < 4; i++) {
        const int c = tid * 4 + i;
        out[row * 1024 + c] = (__bf16)((v[i] - mu) * inv * (float)g[c] + (float)b[c]);
    }
}

// ---------------------------------------------------------------------------
// MFMA GEMM: C[M,N] = A[M,K] @ B[N,K]^T, bf16 in, fp32 acc, OutT out.
// 128x128 tile, BK=32, 256 threads (4 waves 2x2), 4x4 16x16x32 MFMA per wave.
// Round-5 structure (on top of round-4's proven distinct-buffer pipeline):
//   - T2 LDS swizzle, both-sides (rule 21): LDS stays LINEAR (global_load_lds
//     requirement); the GLOBAL source is inverse-permuted (thread tid fetches
//     col-group (tid&3)^((tid>>3)&3)) and fragment reads use slot
//     lq^((lm>>1)&3). Involution verified; 8-way bank conflict -> 2-way (free).
//   - T5 s_setprio(1) around the MFMA cluster (pipeline has stager/MFMA wave
//     role diversity now -> m224 regime).
//   - 3 distinct LDS buffers, K-loop unrolled x3, counted vmcnt(4) (round 4).
//   - XCD-aware 8x8 super-tile block swizzle (round 2).
enum { EP_NONE = 0, EP_ELU1 = 1, EP_BIAS_GELU = 2, EP_BIAS_RES = 3, EP_QKV = 4 };

#define READMM(RA, RB)                                                        \
    do {                                                                      \
        bf16x8 af_[4], bfv_[4];                                               \
        _Pragma("unroll") for (int i_ = 0; i_ < 4; i_++) {                    \
            af_[i_]  = *(const bf16x8*)&RA[(wm * 64 + i_ * 16 + lm) * 32 + swz]; \
            bfv_[i_] = *(const bf16x8*)&RB[(wn * 64 + i_ * 16 + lm) * 32 + swz]; \
        }                                                                     \
        _Pragma("unroll") for (int i_ = 0; i_ < 4; i_++)                      \
            _Pragma("unroll") for (int j_ = 0; j_ < 4; j_++)                  \
                acc[i_][j_] = __builtin_amdgcn_mfma_f32_16x16x32_bf16(        \
                    af_[i_], bfv_[j_], acc[i_][j_], 0, 0, 0);                 \
    } while (0)

#define KBODY(RA, RB, SA, SB, TS, WAITN)                                      \
    do {                                                                      \
        asm volatile("s_waitcnt vmcnt(" #WAITN ")" ::: "memory");             \
        __builtin_amdgcn_s_barrier();                                         \
        __builtin_amdgcn_sched_barrier(0);                                    \
        if ((TS) < nt) {                                                      \
            const int k0_ = (TS) << 5;                                        \
            gload_lds16(pa0 + k0_, &SA[tid * 8]);                             \
            gload_lds16(pa1 + k0_, &SA[2048 + tid * 8]);                      \
            gload_lds16(pb0 + k0_, &SB[tid * 8]);                             \
            gload_lds16(pb1 + k0_, &SB[2048 + tid * 8]);                      \
        }                                                                     \
        __builtin_amdgcn_s_setprio(1);                                        \
        READMM(RA, RB);                                                       \
        __builtin_amdgcn_s_setprio(0);                                        \
    } while (0)

template <int EP, typename OutT>
__global__ __launch_bounds__(256, 3) void gemm_bt(
    const __bf16* __restrict__ A, const __bf16* __restrict__ B,
    const __bf16* __restrict__ bias, const float* __restrict__ resid,
    OutT* __restrict__ C, int M, int N, int K) {
    const int gx = gridDim.x, gy = gridDim.y;
    int bm = blockIdx.y, bn = blockIdx.x;
    {   // bijective XCD-chunked 8x8 super-tile remap (requires gx%8==0, nwg%64==0)
        const int nwg = gx * gy;
        if ((gx & 7) == 0 && (nwg & 63) == 0) {
            const int bid = bm * gx + bn;
            const int perx = nwg >> 3;                 // blocks per XCD
            const int gid = (bid & 7) * perx + (bid >> 3);
            const int stg = gid >> 6, pos = gid & 63;  // super-tile id / pos in 8x8
            const int stw = gx >> 3;                   // super-tiles per grid row
            bm = (stg / stw) * 8 + (pos >> 3);
            bn = (stg % stw) * 8 + (pos & 7);
        }
    }
    const int tid = threadIdx.x;
    const int wave = tid >> 6, lane = tid & 63;
    const int wm = wave & 1, wn = wave >> 1;
    const int lm = lane & 15, lq = lane >> 4;
    // T2 read-side swizzle: physical 16B-slot = lq ^ ((row>>1)&3); row-dependent
    // part reduces to (lm>>1)&3 (i*16 and wm*64 vanish mod 4 after >>1).
    const int swz = (lq ^ ((lm >> 1) & 3)) * 8;

    // three distinct K-tile buffers per operand: compile-time disjoint objects
    // (this is what lets the waitcnt pass keep prefetches in flight - round 4)
    __shared__ __align__(16) __bf16 As0[128 * 32];
    __shared__ __align__(16) __bf16 As1[128 * 32];
    __shared__ __align__(16) __bf16 As2[128 * 32];
    __shared__ __align__(16) __bf16 Bs0[128 * 32];
    __shared__ __align__(16) __bf16 Bs1[128 * 32];
    __shared__ __align__(16) __bf16 Bs2[128 * 32];

    f32x4 acc[4][4] = {};

    // staging: thread tid covers row sr=tid>>2; T2 source-side swizzle picks
    // col-group (tid&3)^((tid>>3)&3) (involution; same 64B line -> coalesced).
    // LDS dest stays tid*16B linear (global_load_lds requirement).
    const int sr = tid >> 2;
    const int sc = (((tid & 3) ^ ((tid >> 3) & 3)) << 3);

    const __bf16* pa0 = A + (size_t)(bm * 128 + sr) * K + sc;
    const __bf16* pa1 = pa0 + (size_t)64 * K;
    const __bf16* pb0 = B + (size_t)(bn * 128 + sr) * K + sc;
    const __bf16* pb1 = pb0 + (size_t)64 * K;

    const int nt = K >> 5;

    // prologue: stage tiles 0,1 (8 loads in flight)
    gload_lds16(pa0, &As0[tid * 8]);
    gload_lds16(pa1, &As0[2048 + tid * 8]);
    gload_lds16(pb0, &Bs0[tid * 8]);
    gload_lds16(pb1, &Bs0[2048 + tid * 8]);
    if (nt > 1) {
        gload_lds16(pa0 + 32, &As1[tid * 8]);
        gload_lds16(pa1 + 32, &As1[2048 + tid * 8]);
        gload_lds16(pb0 + 32, &Bs1[tid * 8]);
        gload_lds16(pb1 + 32, &Bs1[2048 + tid * 8]);
    }

    int t = 0;
    for (; t + 2 < nt; t += 3) {
        KBODY(As0, Bs0, As2, Bs2, t + 2, 4);
        KBODY(As1, Bs1, As0, Bs0, t + 3, 4);
        KBODY(As2, Bs2, As1, Bs1, t + 4, 4);
    }
    // tail (t is a multiple of 3 -> current buffer is #0); safe full drains
    if (t < nt) {
        asm volatile("s_waitcnt vmcnt(0)" ::: "memory");
        __builtin_amdgcn_s_barrier();
        __builtin_amdgcn_sched_barrier(0);
        READMM(As0, Bs0);
        t++;
        if (t < nt) { READMM(As1, Bs1); }
    }

    const int row0 = bm * 128 + wm * 64;
    const int col0 = bn * 128 + wn * 64;
#pragma unroll
    for (int i = 0; i < 4; i++) {
#pragma unroll
        for (int j = 0; j < 4; j++) {
            const int col = col0 + j * 16 + lm;
#pragma unroll
            for (int r = 0; r < 4; r++) {
                const int row = row0 + i * 16 + lq * 4 + r;
                float v = acc[i][j][r];
                if (EP == EP_QKV) {
                    // fused QKV: col region 0/1/2 -> Q/K/V outputs [8192,1024];
                    // elu+1 on Q,K only. Region is block-uniform (col0 step 64).
                    float vv = (col < 2048) ? ((v > 0.0f) ? (v + 1.0f) : expf(v)) : v;
                    __bf16* dst = (col < 1024) ? (__bf16*)C
                                : (col < 2048) ? (__bf16*)const_cast<__bf16*>(bias)
                                               : (__bf16*)const_cast<float*>(resid);
                    dst[(size_t)row * 1024 + (col & 1023)] = (__bf16)vv;
                } else {
                    if (EP == EP_ELU1) {
                        v = (v > 0.0f) ? (v + 1.0f) : expf(v);  // elu(x)+1
                    } else if (EP == EP_BIAS_GELU) {
                        v += (float)bias[col];
                        v = 0.5f * v * (1.0f + erff(v * 0.70710678118654752f));
                    } else if (EP == EP_BIAS_RES) {
                        v += (float)bias[col];
                        v += resid[(size_t)row * N + col];
                    }
                    C[(size_t)row * N + col] = (OutT)v;
                }
            }
        }
    }
}

// ---------------------------------------------------------------------------
// KV partials: block (nh, sc) computes KV[d,v] over 256 s-rows, plus Ksum
__global__ __launch_bounds__(256) void kv_kernel(const __bf16* __restrict__ Kf,
                                                 const __bf16* __restrict__ Vf,
                                                 float* __restrict__ pkv,
                                                 float* __restrict__ pks) {
    const int nh = blockIdx.x, sc = blockIdx.y;
    const int n = nh >> 3, h = nh & 7;
    const int tid = threadIdx.x;
    const int tv = tid & 15, td = tid >> 4;
    __shared__ __align__(16) __bf16 Kt[32 * 128];
    __shared__ __align__(16) __bf16 Vt[32 * 128];
    float acc[8][8] = {};
    float ks[8] = {};
    const size_t rowbase = (size_t)n * 4096 + (size_t)sc * 256;
    for (int s0 = 0; s0 < 256; s0 += 32) {
#pragma unroll
        for (int rep = 0; rep < 2; rep++) {
            const int s = tid + rep * 256;
            const int r = s >> 4, cs = (s & 15) * 8;
            const size_t gidx = (rowbase + s0 + r) * 1024 + h * 128 + cs;
            *(bf16x8*)&Kt[r * 128 + cs] = *(const bf16x8*)&Kf[gidx];
            *(bf16x8*)&Vt[r * 128 + cs] = *(const bf16x8*)&Vf[gidx];
        }
        __syncthreads();
#pragma unroll 4
        for (int s = 0; s < 32; s++) {
            const bf16x8 k8 = *(const bf16x8*)&Kt[s * 128 + td * 8];
            const bf16x8 v8 = *(const bf16x8*)&Vt[s * 128 + tv * 8];
            float kk[8], vv[8];
#pragma unroll
            for (int i = 0; i < 8; i++) { kk[i] = (float)k8[i]; vv[i] = (float)v8[i]; }
#pragma unroll
            for (int i = 0; i < 8; i++) {
                ks[i] += kk[i];
#pragma unroll
                for (int j = 0; j < 8; j++) acc[i][j] += kk[i] * vv[j];
            }
        }
        __syncthreads();
    }
    float* dst = pkv + ((size_t)sc * 16 + nh) * 16384;
#pragma unroll
    for (int i = 0; i < 8; i++)
#pragma unroll
        for (int j = 0; j < 8; j++)
            dst[(td * 8 + i) * 128 + tv * 8 + j] = acc[i][j];
    if (tv == 0) {
        float* ds2 = pks + ((size_t)sc * 16 + nh) * 128;
#pragma unroll
        for (int i = 0; i < 8; i++) ds2[td * 8 + i] = ks[i];
    }
}

__global__ __launch_bounds__(256) void kv_reduce(const float* __restrict__ pkv,
                                                 const float* __restrict__ pks,
                                                 __bf16* __restrict__ kvb,
                                                 float* __restrict__ ksf) {
    const int idx = blockIdx.x * 256 + threadIdx.x;
    float s = 0.0f;
#pragma unroll
    for (int c = 0; c < 16; c++) s += pkv[(size_t)c * 262144 + idx];
    kvb[idx] = (__bf16)s;
    if (idx < 2048) {
        float t = 0.0f;
#pragma unroll
        for (int c = 0; c < 16; c++) t += pks[c * 2048 + idx];
        ksf[idx] = t;
    }
}

__global__ __launch_bounds__(256) void z_kernel(const __bf16* __restrict__ Qf,
                                                const float* __restrict__ ksf,
                                                float* __restrict__ zbuf) {
    const int idx = blockIdx.x * 256 + threadIdx.x;
    const int h = idx & 7;
    const size_t row = (size_t)(idx >> 3);
    const __bf16* q = Qf + row * 1024 + h * 128;
    const float* ks = ksf + ((size_t)((row >> 12) * 8 + h)) * 128;
    float s = 0.0f;
    for (int d = 0; d < 128; d += 8) {
        const bf16x8 q8 = *(const bf16x8*)&q[d];
#pragma unroll
        for (int j = 0; j < 8; j++) s += (float)q8[j] * ks[d + j];
    }
    zbuf[idx] = 1.0f / (s + 1e-6f);
}

// attn out + residual: xmid = x + (Q @ KV) * z   (per head), fp32 out
__global__ __launch_bounds__(256, 2) void attn_out_kernel(
    const __bf16* __restrict__ x, const __bf16* __restrict__ Qf,
    const __bf16* __restrict__ kvb, const float* __restrict__ zbuf,
    float* __restrict__ xmid) {
    const int nh = blockIdx.x, lc = blockIdx.y;
    const int n = nh >> 3, h = nh & 7;
    const int tid = threadIdx.x;
    __shared__ __align__(16) __bf16 KVs[128 * 128];
    __shared__ __align__(16) __bf16 Qs[64 * 128];
    __shared__ float Zs[64];
    const __bf16* kv = kvb + (size_t)nh * 16384;
    for (int i = tid * 8; i < 16384; i += 2048)
        *(bf16x8*)&KVs[i] = *(const bf16x8*)&kv[i];
    const size_t gr0 = (size_t)n * 4096 + (size_t)lc * 64;
#pragma unroll
    for (int rep = 0; rep < 4; rep++) {
        const int s = tid + rep * 256;
        const int r = s >> 4, cs = (s & 15) * 8;
        *(bf16x8*)&Qs[r * 128 + cs] = *(const bf16x8*)&Qf[(gr0 + r) * 1024 + h * 128 + cs];
    }
    if (tid < 64) Zs[tid] = zbuf[(gr0 + tid) * 8 + h];
    __syncthreads();
    const int tv = (tid & 15) * 8;
    const int tr0 = (tid >> 4) * 4;
    float acc[4][8] = {};
    for (int d = 0; d < 128; d++) {
        const bf16x8 kv8 = *(const bf16x8*)&KVs[d * 128 + tv];
        float kf[8];
#pragma unroll
        for (int j = 0; j < 8; j++) kf[j] = (float)kv8[j];
#pragma unroll
        for (int rr = 0; rr < 4; rr++) {
            const float q = (float)Qs[(tr0 + rr) * 128 + d];
#pragma unroll
            for (int j = 0; j < 8; j++) acc[rr][j] += q * kf[j];
        }
    }
#pragma unroll
    for (int rr = 0; rr < 4; rr++) {
        const size_t gi = (gr0 + tr0 + rr) * 1024 + h * 128 + tv;
        const float z = Zs[tr0 + rr];
        const bf16x8 xr = *(const bf16x8*)&x[gi];
#pragma unroll
        for (int j = 0; j < 8; j++) xmid[gi + j] = (float)xr[j] + acc[rr][j] * z;
    }
}

// ---------------------------------------------------------------------------
extern "C" void kernel_launch(void* const* d_in, const int* in_sizes, int n_in,
                              void* d_out, int out_size, void* d_ws, size_t ws_size,
                              hipStream_t stream) {
    float* out = (float*)d_out;   // <-- output is FP32 (reference output dtype)
    char* ws = (char*)d_ws;

    const int nx = 8388608, nw = 1048576, nw1 = 4194304, nb1 = 4096, ng = 1024;
    size_t off = 0;
    __bf16* cx   = (__bf16*)(ws + off); off += (size_t)nx * 2;
    __bf16* cwq  = (__bf16*)(ws + off); off += (size_t)nw * 2;   // cwq/cwk/cwv
    __bf16* cwk  = (__bf16*)(ws + off); off += (size_t)nw * 2;   // contiguous =
    __bf16* cwv  = (__bf16*)(ws + off); off += (size_t)nw * 2;   // B[3072,1024]
    __bf16* cw1  = (__bf16*)(ws + off); off += (size_t)nw1 * 2;
    __bf16* cb1  = (__bf16*)(ws + off); off += (size_t)nb1 * 2;
    __bf16* cw2  = (__bf16*)(ws + off); off += (size_t)nw1 * 2;
    __bf16* cb2  = (__bf16*)(ws + off); off += (size_t)ng * 2;
    __bf16* cg1  = (__bf16*)(ws + off); off += (size_t)ng * 2;
    __bf16* cbe1 = (__bf16*)(ws + off); off += (size_t)ng * 2;
    __bf16* cg2  = (__bf16*)(ws + off); off += (size_t)ng * 2;
    __bf16* cbe2 = (__bf16*)(ws + off); off += (size_t)ng * 2;
    int* flags = (int*)(ws + off); off += 64;

    char* PB = ws + off;
    __bf16* x2   = (__bf16*)(PB);                 // LN1 out; later LN2 out
    __bf16* Qf   = (__bf16*)(PB + 16777216);
    float*  pkv  = (float*)(PB + 33554432);
    __bf16* hbuf = (__bf16*)(PB + 16777216);      // MLP h chunk (over Qf+pkv)
    __bf16* Kf   = (__bf16*)(PB + 50331648);
    __bf16* Vf   = (__bf16*)(PB + 67108864);
    float*  xmid = (float*)(PB + 50331648);       // fp32 (over Kf+Vf)
    float*  pks  = (float*)(PB + 83886080);
    float*  ksf  = (float*)(PB + 84017152);
    float*  zbuf = (float*)(PB + 84025344);
    __bf16* kvb  = (__bf16*)(PB + 84287488);      // ends PB+84,811,776

    // 0. sniff dtype + canonicalize inputs to bf16
    sniff_kernel<<<1, 256, 0, stream>>>((const unsigned short*)d_in[0], flags);
    convert_kernel<<<nx / 2048, 256, 0, stream>>>(d_in[0], cx, nx, flags);
    convert_kernel<<<nw / 2048, 256, 0, stream>>>(d_in[1], cwq, nw, flags);
    convert_kernel<<<nw / 2048, 256, 0, stream>>>(d_in[2], cwk, nw, flags);
    convert_kernel<<<nw / 2048, 256, 0, stream>>>(d_in[3], cwv, nw, flags);
    convert_kernel<<<nw1 / 2048, 256, 0, stream>>>(d_in[4], cw1, nw1, flags);
    convert_kernel<<<2, 256, 0, stream>>>(d_in[5], cb1, nb1, flags);
    convert_kernel<<<nw1 / 2048, 256, 0, stream>>>(d_in[6], cw2, nw1, flags);
    convert_kernel<<<1, 256, 0, stream>>>(d_in[7], cb2, ng, flags);
    convert_kernel<<<1, 256, 0, stream>>>(d_in[8], cg1, ng, flags);
    convert_kernel<<<1, 256, 0, stream>>>(d_in[9], cbe1, ng, flags);
    convert_kernel<<<1, 256, 0, stream>>>(d_in[10], cg2, ng, flags);
    convert_kernel<<<1, 256, 0, stream>>>(d_in[11], cbe2, ng, flags);

    // 1. LN1
    ln_kernel<__bf16><<<8192, 256, 0, stream>>>(cx, cg1, cbe1, x2);
    // 2. fused QKV projection: B = [wq;wk;wv] (contiguous), N=3072.
    //    Epilogue routes col regions to Qf/Kf/Vf; elu+1 on Q,K (v/L*L cancels).
    gemm_bt<EP_QKV, __bf16><<<dim3(3072 / 128, 8192 / 128), 256, 0, stream>>>(
        x2, cwq, (const __bf16*)Kf, (const float*)Vf, Qf, 8192, 3072, 1024);
    // 3. KV + Ksum
    kv_kernel<<<dim3(16, 16), 256, 0, stream>>>(Kf, Vf, pkv, pks);
    kv_reduce<<<1024, 256, 0, stream>>>(pkv, pks, kvb, ksf);
    // 4. Z, attention out + residual -> xmid fp32 (over dead Kf/Vf)
    z_kernel<<<256, 256, 0, stream>>>(Qf, ksf, zbuf);
    attn_out_kernel<<<dim3(16, 64), 256, 0, stream>>>(cx, Qf, kvb, zbuf, xmid);
    // 5. LN2 + chunked MLP; final epilogue writes FP32 out
    ln_kernel<float><<<8192, 256, 0, stream>>>(xmid, cg2, cbe2, x2);
    for (int c = 0; c < 2; c++) {
        const size_t ro = (size_t)c * 4096;
        gemm_bt<EP_BIAS_GELU, __bf16><<<dim3(4096 / 128, 4096 / 128), 256, 0, stream>>>(
            x2 + ro * 1024, cw1, cb1, nullptr, hbuf, 4096, 4096, 1024);
        gemm_bt<EP_BIAS_RES, float><<<dim3(1024 / 128, 4096 / 128), 256, 0, stream>>>(
            hbuf, cw2, cb2, xmid + ro * 1024, out + ro * 1024, 4096, 1024, 4096);
    }
}